// Round 15
// baseline (290.708 us; speedup 1.0000x reference)
//
#include <hip/hip_runtime.h>

#define S_LEN 2048
#define DMODEL 4096
#define NH 32
#define NKV 8
#define DH 128
#define QDIM (NH*DH)      // 4096
#define NQKV 6144         // fused projection width
#define SCALE 0.08838834764831845f

typedef __attribute__((ext_vector_type(8))) short short8;
typedef __attribute__((ext_vector_type(4))) float f32x4;
typedef __attribute__((ext_vector_type(4))) unsigned short us4;

__device__ __forceinline__ unsigned short f2bf(float f) {
  union { float f; unsigned int u; } v; v.f = f;
  unsigned int r = v.u + 0x7FFFu + ((v.u >> 16) & 1u);
  return (unsigned short)(r >> 16);
}
__device__ __forceinline__ float bf2f(unsigned short h) {
  union { unsigned int u; float f; } v; v.u = ((unsigned int)h) << 16;
  return v.f;
}

// ---------------- fused f32 -> bf16 convert: x, Wq, Wk, Wv (Wo is converted in attn_fwd) ----
__global__ __launch_bounds__(256) void cvt_all(const float* __restrict__ x,
                                               const float* __restrict__ Wq,
                                               const float* __restrict__ Wk,
                                               const float* __restrict__ Wv,
                                               unsigned short* __restrict__ xb,
                                               unsigned short* __restrict__ Wqkvb) {
  const int blk = blockIdx.x;
  const float* src; unsigned short* dst; int off;
  if (blk < 8192)       { src = x;  dst = xb;               off = blk; }
  else if (blk < 24576) { src = Wq; dst = Wqkvb;            off = blk - 8192; }
  else if (blk < 28672) { src = Wk; dst = Wqkvb + 16777216; off = blk - 24576; }
  else                  { src = Wv; dst = Wqkvb + 20971520; off = blk - 28672; }
  int i = off * 256 + threadIdx.x;
  const float4 f = reinterpret_cast<const float4*>(src)[i];
  us4 o;
  o.x = f2bf(f.x); o.y = f2bf(f.y); o.z = f2bf(f.z); o.w = f2bf(f.w);
  reinterpret_cast<us4*>(dst)[i] = o;
}

// ---------------- (BM x BN) 8-phase GEMM, 2-buffer, EVENED MFMA phases ----------------
// Per K-tile: 4 equal m-groups (MG=MI/4 frags each), MFMA count identical per phase.
//   ph1{read af[0:2MG]+bf[all]; bar; MFMA g0; bar}  ph2{read af[2MG:4MG]; bar; MFMA g1; bar}
//   ph3{stage A(t+2); MFMA g2; bar}                 ph4{stage B(t+2); MFMA g3; vmcnt(VM); bar}
// Staging/barrier/vmcnt placement byte-identical to the round-8/10 proven schedule;
// only the MFMA grouping changed (8/16/8/16 -> even). Accumulator chains unchanged.
template<int M_, int N_, int K_, int BM_, int BN_, int OUT_BF16, int CHN>
__global__ __launch_bounds__(512) void gemm8p(const unsigned short* __restrict__ A,
                                              const unsigned short* __restrict__ B,
                                              void* __restrict__ Cv) {
  constexpr int ATILE = BM_ * 128;
  constexpr int BTILE = BN_ * 128;
  constexpr int BUF = ATILE + BTILE;
  constexpr int LPA = BM_ / 64;
  constexpr int LPB = BN_ / 64;
  constexpr int VM  = LPA + LPB;
  constexpr int MI = BM_ / 32, NF = BN_ / 64;
  constexpr int MG = MI / 4;             // m-frags per phase group (2 for BM=256, 1 for BM=128)
  constexpr int NT = K_ / 64;
  __shared__ char lds[2 * BUF];

  const int tid = threadIdx.x;
  const int lane = tid & 63, wave = tid >> 6;
  const int wm = wave >> 2, wn = wave & 3;
  const int fr = lane & 15, fq = lane >> 4;

  const int lin = blockIdx.x;
  const int xcd = lin & 7;
  const int slot = lin >> 3;
  const long n0 = (long)(xcd * CHN + slot % CHN) * BN_;
  const long m0 = (long)(slot / CHN) * BM_;

  auto STAGE_A = [&](int t, int c) {
#pragma unroll
    for (int u = 0; u < LPA; ++u) {
      int b = u * 8192 + tid * 16;
      int row = b >> 7;
      int off = (b & 127) ^ ((row & 7) << 4);
      __builtin_amdgcn_global_load_lds(
        (const __attribute__((address_space(1))) void*)((const char*)A + ((m0 + row) * (long)K_ + t * 64) * 2 + off),
        (__attribute__((address_space(3))) void*)(lds + c * BUF + b), 16, 0, 0);
    }
  };
  auto STAGE_B = [&](int t, int c) {
#pragma unroll
    for (int u = 0; u < LPB; ++u) {
      int b = u * 8192 + tid * 16;
      int row = b >> 7;
      int off = (b & 127) ^ ((row & 7) << 4);
      __builtin_amdgcn_global_load_lds(
        (const __attribute__((address_space(1))) void*)((const char*)B + ((n0 + row) * (long)K_ + t * 64) * 2 + off),
        (__attribute__((address_space(3))) void*)(lds + c * BUF + ATILE + b), 16, 0, 0);
    }
  };
#define VMCNT_STEADY() do { if constexpr (VM == 6) asm volatile("s_waitcnt vmcnt(6)" ::: "memory"); \
                            else if constexpr (VM == 7) asm volatile("s_waitcnt vmcnt(7)" ::: "memory"); \
                            else asm volatile("s_waitcnt vmcnt(8)" ::: "memory"); } while (0)
#define MFMA_GROUP(g) do { \
  __builtin_amdgcn_s_setprio(1); \
  _Pragma("unroll") \
  for (int mi = (g) * MG; mi < ((g) + 1) * MG; ++mi) \
    _Pragma("unroll") \
    for (int ni = 0; ni < NF; ++ni) \
      _Pragma("unroll") \
      for (int ks = 0; ks < 2; ++ks) \
        acc[mi][ni] = __builtin_amdgcn_mfma_f32_16x16x32_bf16(af[mi][ks], bf[ni][ks], acc[mi][ni], 0, 0, 0); \
  __builtin_amdgcn_s_setprio(0); \
} while (0)

  f32x4 acc[MI][NF] = {};
  short8 af[MI][2];
  short8 bf[NF][2];

  STAGE_A(0, 0); STAGE_B(0, 0);
  STAGE_A(1, 1); STAGE_B(1, 1);
  VMCNT_STEADY();
  __builtin_amdgcn_s_barrier();

  for (int t = 0; t < NT; ++t) {
    const int c = t & 1;
    const char* tb = lds + c * BUF;

    // ---- ph1: read af[0:2MG] + all bf; MFMA group 0 ----
#pragma unroll
    for (int mi = 0; mi < 2 * MG; ++mi) {
      int row = wm * (BM_ / 2) + mi * 16 + fr;
#pragma unroll
      for (int ks = 0; ks < 2; ++ks)
        af[mi][ks] = *(const short8*)(tb + row * 128 + ((ks * 64 + fq * 16) ^ ((row & 7) << 4)));
    }
#pragma unroll
    for (int ni = 0; ni < NF; ++ni) {
      int row = wn * (BN_ / 4) + ni * 16 + fr;
#pragma unroll
      for (int ks = 0; ks < 2; ++ks)
        bf[ni][ks] = *(const short8*)(tb + ATILE + row * 128 + ((ks * 64 + fq * 16) ^ ((row & 7) << 4)));
    }
    __builtin_amdgcn_s_barrier();
    MFMA_GROUP(0);
    __builtin_amdgcn_s_barrier();

    // ---- ph2: read af[2MG:4MG]; MFMA group 1 ----
#pragma unroll
    for (int mi = 2 * MG; mi < 4 * MG; ++mi) {
      int row = wm * (BM_ / 2) + mi * 16 + fr;
#pragma unroll
      for (int ks = 0; ks < 2; ++ks)
        af[mi][ks] = *(const short8*)(tb + row * 128 + ((ks * 64 + fq * 16) ^ ((row & 7) << 4)));
    }
    __builtin_amdgcn_s_barrier();
    MFMA_GROUP(1);
    __builtin_amdgcn_s_barrier();

    // ---- ph3: stage A(t+2) into buf c (all buf-c reads done); MFMA group 2 ----
    if (t + 2 < NT) STAGE_A(t + 2, c);
    MFMA_GROUP(2);
    __builtin_amdgcn_s_barrier();

    // ---- ph4: stage B(t+2); MFMA group 3; counted vmcnt ----
    if (t + 2 < NT) STAGE_B(t + 2, c);
    MFMA_GROUP(3);
    if (t + 2 < NT) { VMCNT_STEADY(); }
    else if (t + 1 < NT) { asm volatile("s_waitcnt vmcnt(0)" ::: "memory"); }
    __builtin_amdgcn_s_barrier();
  }
#undef VMCNT_STEADY
#undef MFMA_GROUP

#pragma unroll
  for (int mi = 0; mi < MI; ++mi)
#pragma unroll
    for (int ni = 0; ni < NF; ++ni)
#pragma unroll
      for (int j = 0; j < 4; ++j) {
        long r = m0 + wm * (BM_ / 2) + mi * 16 + fq * 4 + j;
        long cc = n0 + wn * (BN_ / 4) + ni * 16 + fr;
        float v = acc[mi][ni][j];
        if (OUT_BF16) ((unsigned short*)Cv)[r * N_ + cc] = f2bf(v);
        else          ((float*)Cv)[r * N_ + cc] = v;
      }
}

// ---------------- merged: K-rope (blocks 0..4095) + V transpose (blocks 4096..4607) ----
__global__ __launch_bounds__(256) void ropek_tv(unsigned short* __restrict__ C,
                                                const float* __restrict__ cosb,
                                                const float* __restrict__ sinb,
                                                unsigned short* __restrict__ VT) {
  __shared__ unsigned short tbuf[64][72];
  const int blk = blockIdx.x;
  if (blk < 4096) {
    int idx = blk * 256 + threadIdx.x;   // 2048 s x 8 hh x 64 i
    int i = idx & 63;
    int t = idx >> 6;
    int hh = t & 7;
    int s = t >> 3;
    unsigned short* row = C + (size_t)s * NQKV + 4096 + hh * DH;
    float c  = cosb[s * DH + i];
    float sn = sinb[s * DH + i];
    float x1 = bf2f(row[i]);
    float x2 = bf2f(row[i + 64]);
    row[i]      = f2bf(x1 * c - x2 * sn);
    row[i + 64] = f2bf(x2 * c + x1 * sn);
    return;
  }
  const int b2 = blk - 4096;             // 512 blocks: 32 x 16
  const unsigned short* Vbuf = C + 5120;
  const int s0 = (b2 & 31) * 64, e0 = (b2 >> 5) * 64;
  const int r = threadIdx.x >> 3, c = (threadIdx.x & 7) * 8;
#pragma unroll
  for (int half = 0; half < 2; ++half) {
    int row = r + half * 32;
    *reinterpret_cast<short8*>(&tbuf[row][c]) =
        *reinterpret_cast<const short8*>(Vbuf + (size_t)(s0 + row) * NQKV + e0 + c);
  }
  __syncthreads();
  const int hh = e0 >> 7, dbase = e0 & 127;
#pragma unroll
  for (int half = 0; half < 2; ++half) {
    int row = r + half * 32;
    short8 o;
#pragma unroll
    for (int j = 0; j < 8; ++j) ((unsigned short*)&o)[j] = tbuf[c + j][row];
    *reinterpret_cast<short8*>(VT + (size_t)hh * (DH * (size_t)S_LEN)
                               + (size_t)(dbase + row) * S_LEN + s0 + c) = o;
  }
}

// ---------------- GQA causal flash attention + in-register Q-rope + Wo side-convert ----
__global__ __launch_bounds__(256) void attn_fwd(const unsigned short* __restrict__ C,
                                                const unsigned short* __restrict__ VT,
                                                unsigned short* __restrict__ Ob,
                                                const float* __restrict__ Wo,
                                                unsigned short* __restrict__ Wob,
                                                const float* __restrict__ cosb,
                                                const float* __restrict__ sinb) {
  __shared__ unsigned short KVs[2][8192];   // 16 KB/buf: K[32][128] swz @0, V^T[128][32] swz @8KB
  __shared__ unsigned short Pl[4][16 * 40];
  const int tid = threadIdx.x, lane = tid & 63, wave = tid >> 6;
  const int kvh = blockIdx.x & 7;
  const int p = blockIdx.x >> 3;
  const int h = kvh * 4 + wave;
  const int fr = lane & 15, fq = lane >> 4;
  const int q0s[2] = { p * 16, (127 - p) * 16 };
  const int tilesA = (p * 16 + 47) >> 5;
  const int tilesB = ((127 - p) * 16 + 47) >> 5;

  const unsigned short* Qbase = C + (size_t)h * DH;
  const unsigned short* Kbase = C + 4096 + (size_t)kvh * DH;
  const unsigned short* Vbase = VT + (size_t)kvh * (DH * (size_t)S_LEN);

  const int wq0 = blockIdx.x * 8192 + tid;
  float4 wreg;

  short8 qf[2][4];
#pragma unroll
  for (int s = 0; s < 2; ++s)
#pragma unroll
    for (int dc = 0; dc < 4; ++dc)
      qf[s][dc] = *reinterpret_cast<const short8*>(
          Qbase + (size_t)(q0s[s] + fr) * NQKV + dc * 32 + fq * 8);

  // in-register Q rope + SCALE: pair (d, d+64) = frags (dc, dc+2), same thread
#pragma unroll
  for (int s = 0; s < 2; ++s) {
    const int row = q0s[s] + fr;
#pragma unroll
    for (int dc = 0; dc < 2; ++dc)
#pragma unroll
      for (int e = 0; e < 8; ++e) {
        int d = dc * 32 + fq * 8 + e;
        float cs = cosb[row * DH + d];
        float sn = sinb[row * DH + d];
        float x1 = bf2f((unsigned short)qf[s][dc][e]);
        float x2 = bf2f((unsigned short)qf[s][dc + 2][e]);
        qf[s][dc][e]     = (short)f2bf((x1 * cs - x2 * sn) * SCALE);
        qf[s][dc + 2][e] = (short)f2bf((x2 * cs + x1 * sn) * SCALE);
      }
  }

  f32x4 o_acc[2][8] = {};
  float mrow[2][4] = {{-1e30f,-1e30f,-1e30f,-1e30f},{-1e30f,-1e30f,-1e30f,-1e30f}};
  float lpart[2][4] = {};

  auto STAGE = [&](int t, int buf) {
    const int kv0 = t * 32;
    char* dst = (char*)&KVs[buf][0];
#pragma unroll
    for (int sh = 0; sh < 2; ++sh) {
      int b = sh * 4096 + tid * 16;
      int krow = b >> 8;
      int kcol = (b & 255) ^ ((krow & 7) << 4);
      __builtin_amdgcn_global_load_lds(
          (const __attribute__((address_space(1))) void*)(Kbase + (size_t)(kv0 + krow) * NQKV + (kcol >> 1)),
          (__attribute__((address_space(3))) void*)(dst + b), 16, 0, 0);
      int vrow = b >> 6;
      int vcol = (b & 63) ^ ((((vrow ^ (vrow >> 2)) & 3)) << 4);
      __builtin_amdgcn_global_load_lds(
          (const __attribute__((address_space(1))) void*)(Vbase + (size_t)vrow * S_LEN + kv0 + (vcol >> 1)),
          (__attribute__((address_space(3))) void*)(dst + 8192 + b), 16, 0, 0);
    }
  };

  int cur = 0;
  STAGE(0, 0);
  asm volatile("s_waitcnt vmcnt(0)" ::: "memory");
  __syncthreads();

  for (int t = 0; t < tilesB; ++t) {
    const int kv0 = t * 32;

    // Wo side-convert: store chunk t-1 (completed by last tile's vmcnt(0)), load chunk t
    if (t > 0 && t <= 32) {
      us4 o;
      o.x = f2bf(wreg.x); o.y = f2bf(wreg.y); o.z = f2bf(wreg.z); o.w = f2bf(wreg.w);
      reinterpret_cast<us4*>(Wob)[wq0 + (t - 1) * 256] = o;
    }
    if (t < 32) wreg = reinterpret_cast<const float4*>(Wo)[wq0 + t * 256];

    if (t + 1 < tilesB) STAGE(t + 1, cur ^ 1);
    const char* kvb = (const char*)&KVs[cur][0];

#pragma unroll
    for (int s = 0; s < 2; ++s) {
      if (s == 0 && t >= tilesA) continue;
      const int q0 = q0s[s];

      f32x4 sacc[2] = {};
#pragma unroll
      for (int nt = 0; nt < 2; ++nt) {
        const int row = nt * 16 + fr;
#pragma unroll
        for (int dc = 0; dc < 4; ++dc) {
          short8 kf = *reinterpret_cast<const short8*>(
              kvb + row * 256 + ((dc * 64 + fq * 16) ^ ((row & 7) << 4)));
          sacc[nt] = __builtin_amdgcn_mfma_f32_16x16x32_bf16(qf[s][dc], kf, sacc[nt], 0, 0, 0);
        }
      }

      const bool needMask = (kv0 + 32 > q0);
      if (needMask) {
#pragma unroll
        for (int j = 0; j < 4; ++j) {
          int qrow = q0 + fq * 4 + j;
#pragma unroll
          for (int nt = 0; nt < 2; ++nt)
            sacc[nt][j] = ((kv0 + nt*16 + fr) <= qrow) ? sacc[nt][j] : -1e30f;
        }
      }
      bool ok = true;
      float lm[4];
#pragma unroll
      for (int j = 0; j < 4; ++j) {
        lm[j] = fmaxf(sacc[0][j], sacc[1][j]);
        ok = ok && (lm[j] <= mrow[s][j] + 8.f);
      }
      if (!__all(ok)) {
#pragma unroll
        for (int j = 0; j < 4; ++j) {
          float rm = lm[j];
          rm = fmaxf(rm, __shfl_xor(rm, 1));
          rm = fmaxf(rm, __shfl_xor(rm, 2));
          rm = fmaxf(rm, __shfl_xor(rm, 4));
          rm = fmaxf(rm, __shfl_xor(rm, 8));
          float mnew = fmaxf(mrow[s][j], rm);
          float corr = __expf(mrow[s][j] - mnew);
          mrow[s][j] = mnew;
          lpart[s][j] *= corr;
#pragma unroll
          for (int dt = 0; dt < 8; ++dt) o_acc[s][dt][j] *= corr;
        }
      }
#pragma unroll
      for (int j = 0; j < 4; ++j) {
        float p0 = __expf(sacc[0][j] - mrow[s][j]);
        float p1 = __expf(sacc[1][j] - mrow[s][j]);
        lpart[s][j] += p0 + p1;
        unsigned int u;
        asm("v_cvt_pk_bf16_f32 %0, %1, %2" : "=v"(u) : "v"(p0), "v"(p1));
        Pl[wave][(fq*4 + j)*40 + fr]      = (unsigned short)u;
        Pl[wave][(fq*4 + j)*40 + 16 + fr] = (unsigned short)(u >> 16);
      }
      asm volatile("s_waitcnt lgkmcnt(0)" ::: "memory");
      __builtin_amdgcn_sched_barrier(0);

      short8 pa = *reinterpret_cast<const short8*>(&Pl[wave][fr*40 + fq*8]);
#pragma unroll
      for (int dt = 0; dt < 8; ++dt) {
        const int row = dt * 16 + fr;
        short8 bv = *reinterpret_cast<const short8*>(
            kvb + 8192 + row * 64 + ((fq * 16) ^ ((((row ^ (row >> 2)) & 3)) << 4)));
        o_acc[s][dt] = __builtin_amdgcn_mfma_f32_16x16x32_bf16(pa, bv, o_acc[s][dt], 0, 0, 0);
      }
    }

    asm volatile("s_waitcnt vmcnt(0)" ::: "memory");
    __syncthreads();
    cur ^= 1;
  }

#pragma unroll
  for (int s = 0; s < 2; ++s)
#pragma unroll
    for (int j = 0; j < 4; ++j) {
      float l = lpart[s][j];
      l += __shfl_xor(l, 1);
      l += __shfl_xor(l, 2);
      l += __shfl_xor(l, 4);
      l += __shfl_xor(l, 8);
      float inv = 1.f / l;
      size_t r = (size_t)q0s[s] + fq*4 + j;
#pragma unroll
      for (int dt = 0; dt < 8; ++dt)
        Ob[r * QDIM + h * DH + dt*16 + fr] = f2bf(o_acc[s][dt][j] * inv);
    }
}

// ---------------- launch ----------------
extern "C" void kernel_launch(void* const* d_in, const int* in_sizes, int n_in,
                              void* d_out, int out_size, void* d_ws, size_t ws_size,
                              hipStream_t stream) {
  (void)in_sizes; (void)n_in; (void)out_size; (void)ws_size;
  const float* x    = (const float*)d_in[0];
  const float* Wq   = (const float*)d_in[1];
  const float* Wk   = (const float*)d_in[2];
  const float* Wv   = (const float*)d_in[3];
  const float* Wo   = (const float*)d_in[4];
  const float* cosb = (const float*)d_in[5];
  const float* sinb = (const float*)d_in[6];

  char* ws = (char*)d_ws;
  unsigned short* xb    = (unsigned short*)(ws);               // 16.8 MB (dead after QKV gemm)
  unsigned short* Wqkvb = (unsigned short*)(ws + 16777216);    // 50.3 MB [Wq;Wk;Wv]
  unsigned short* Wob   = (unsigned short*)(ws + 67108864);    // 33.6 MB (written by attn_fwd)
  unsigned short* Cqkv  = (unsigned short*)(ws + 100663296);   // 25.2 MB [Q|K|V] stride 6144
  unsigned short* VT    = (unsigned short*)(ws + 125829120);   // 4.2 MB
  unsigned short* Ab    = xb;                                  // reuse

  cvt_all<<<32768, 256, 0, stream>>>(x, Wq, Wk, Wv, xb, Wqkvb);

  // QKV projection: evened-phase 2-buffer schedule. 256x192 tiles -> 256 blocks.
  gemm8p<2048, 6144, 4096, 256, 192, 1, 4><<<256, 512, 0, stream>>>(xb, Wqkvb, Cqkv);

  // merged K-rope + V-transpose (Q rope happens in-register inside attn_fwd)
  ropek_tv<<<4608, 256, 0, stream>>>(Cqkv, cosb, sinb, VT);

  attn_fwd<<<512, 256, 0, stream>>>(Cqkv, VT, Ab, Wo, Wob, cosb, sinb);

  // Output projection: evened-phase 2-buffer schedule. 128x256 tiles -> 256 blocks.
  gemm8p<2048, 4096, 4096, 128, 256, 0, 2><<<256, 512, 0, stream>>>(Ab, Wob, d_out);
}

// Round 16
// 285.077 us; speedup vs baseline: 1.0198x; 1.0198x over previous
//
#include <hip/hip_runtime.h>

#define S_LEN 2048
#define DMODEL 4096
#define NH 32
#define NKV 8
#define DH 128
#define QDIM (NH*DH)      // 4096
#define NQKV 6144         // fused projection width
#define SCALE 0.08838834764831845f

typedef __attribute__((ext_vector_type(8))) short short8;
typedef __attribute__((ext_vector_type(4))) float f32x4;
typedef __attribute__((ext_vector_type(4))) unsigned short us4;

__device__ __forceinline__ unsigned short f2bf(float f) {
  union { float f; unsigned int u; } v; v.f = f;
  unsigned int r = v.u + 0x7FFFu + ((v.u >> 16) & 1u);
  return (unsigned short)(r >> 16);
}
__device__ __forceinline__ float bf2f(unsigned short h) {
  union { unsigned int u; float f; } v; v.u = ((unsigned int)h) << 16;
  return v.f;
}
__device__ __forceinline__ short8 pack_bf16x8(float4 a, float4 b) {
  unsigned int u0, u1, u2, u3;
  asm("v_cvt_pk_bf16_f32 %0, %1, %2" : "=v"(u0) : "v"(a.x), "v"(a.y));
  asm("v_cvt_pk_bf16_f32 %0, %1, %2" : "=v"(u1) : "v"(a.z), "v"(a.w));
  asm("v_cvt_pk_bf16_f32 %0, %1, %2" : "=v"(u2) : "v"(b.x), "v"(b.y));
  asm("v_cvt_pk_bf16_f32 %0, %1, %2" : "=v"(u3) : "v"(b.z), "v"(b.w));
  union { unsigned int u[4]; short8 s; } r;
  r.u[0] = u0; r.u[1] = u1; r.u[2] = u2; r.u[3] = u3;
  return r.s;
}

// ---------------- f32 -> bf16 convert: x only (W handled in-GEMM / in-attn) ----------------
__global__ __launch_bounds__(256) void cvt_x(const float* __restrict__ in,
                                             unsigned short* __restrict__ out) {
  int i = blockIdx.x * 256 + threadIdx.x;
  const float4 f = reinterpret_cast<const float4*>(in)[i];
  us4 o;
  o.x = f2bf(f.x); o.y = f2bf(f.y); o.z = f2bf(f.z); o.w = f2bf(f.w);
  reinterpret_cast<us4*>(out)[i] = o;
}

// ---------------- QKV GEMM: 256x192 tiles, B staged DIRECTLY from f32 weights ----------------
// C[2048,6144] = xb[2048,4096](bf16) * [Wq;Wk;Wv][6144,4096]^T (f32).
// B pipeline (counted vmcnt, never 0 in steady state):
//   ph1(t): ds_reads; vmcnt(4) [drains B-f32(t+1), leaves A(t+1)];
//           cvt+ds_write B(t+1) -> buf[(t+1)&1]; issue B-f32(t+2); bar; MFMA; bar
//   ph3(t): A(t+2) via global_load_lds -> buf[t&1]
//   ph4(t): MFMA; vmcnt(10) [drains A(t+1), leaves B-f32(t+2)+A(t+2)]; bar
// Write->read visibility: B(t+1) ds_writes complete before ph2(t)'s ds_read waits (DS in-order),
// published by the intervening barriers; buf[(t+1)&1]'s prior reads ended at ph2-end(t-1).
__global__ __launch_bounds__(512) void gemm8pqkv(const unsigned short* __restrict__ A,
                                                 const float* __restrict__ Wq,
                                                 const float* __restrict__ Wk,
                                                 const float* __restrict__ Wv,
                                                 unsigned short* __restrict__ Cv) {
  constexpr int K_ = 4096, N_ = 6144;
  constexpr int BM_ = 256, BN_ = 192;
  constexpr int ATILE = BM_ * 128;       // 32 KB
  constexpr int BTILE = BN_ * 128;       // 24 KB
  constexpr int BUF = ATILE + BTILE;     // 56 KB
  constexpr int LPA = BM_ / 64;          // 4
  constexpr int LPB = BN_ / 64;          // 3 write-slots (short8); 6 f32x4 loads
  constexpr int MI = 8, NF = 3;
  constexpr int MIL = 4, NFL = 1;
  constexpr int NT = K_ / 64;            // 64
  constexpr int CHN = 4;
  __shared__ char lds[2 * BUF];

  const int tid = threadIdx.x;
  const int lane = tid & 63, wave = tid >> 6;
  const int wm = wave >> 2, wn = wave & 3;
  const int fr = lane & 15, fq = lane >> 4;

  const int lin = blockIdx.x;
  const int xcd = lin & 7;
  const int slot = lin >> 3;
  const long n0 = (long)(xcd * CHN + slot % CHN) * BN_;
  const long m0 = (long)(slot / CHN) * BM_;

  // per-slot B f32 source pointers (swizzle folded into the global column)
  const char* pB[LPB];
  int bslot[LPB];
#pragma unroll
  for (int u = 0; u < LPB; ++u) {
    int b = u * 8192 + tid * 16;
    int row = b >> 7;
    int colx = (b & 127) ^ ((row & 7) << 4);
    long n = n0 + row;
    const float* base = (n < 4096) ? Wq + n * (long)K_
                      : (n < 5120) ? Wk + (n - 4096) * (long)K_
                                   : Wv + (n - 5120) * (long)K_;
    pB[u] = (const char*)base + (long)colx * 2;
    bslot[u] = b;
  }
  float4 breg[LPB][2];

  auto B_ISSUE = [&](int t) {
#pragma unroll
    for (int u = 0; u < LPB; ++u) {
      breg[u][0] = *reinterpret_cast<const float4*>(pB[u] + (long)t * 256);
      breg[u][1] = *reinterpret_cast<const float4*>(pB[u] + (long)t * 256 + 16);
    }
  };
  auto B_WRITE = [&](int c) {
#pragma unroll
    for (int u = 0; u < LPB; ++u)
      *reinterpret_cast<short8*>(lds + c * BUF + ATILE + bslot[u]) =
          pack_bf16x8(breg[u][0], breg[u][1]);
  };
  auto STAGE_A = [&](int t, int c) {
#pragma unroll
    for (int u = 0; u < LPA; ++u) {
      int b = u * 8192 + tid * 16;
      int row = b >> 7;
      int off = (b & 127) ^ ((row & 7) << 4);
      __builtin_amdgcn_global_load_lds(
        (const __attribute__((address_space(1))) void*)((const char*)A + ((m0 + row) * (long)K_ + t * 64) * 2 + off),
        (__attribute__((address_space(3))) void*)(lds + c * BUF + b), 16, 0, 0);
    }
  };

  f32x4 acc[MI][NF] = {};
  short8 af[MI][2];
  short8 bf[NF][2];

  // prologue: B(0), B(1) via regs (cold-start drains); A(0), A(1) via gload_lds
  B_ISSUE(0);
  asm volatile("s_waitcnt vmcnt(0)" ::: "memory");
  B_WRITE(0);
  B_ISSUE(1);
  STAGE_A(0, 0); STAGE_A(1, 1);
  asm volatile("s_waitcnt vmcnt(8)" ::: "memory");   // B-f32(1) done (oldest 6 of 14)
  B_WRITE(1);
  asm volatile("s_waitcnt vmcnt(0)" ::: "memory");   // drain A(0), A(1)
  asm volatile("s_waitcnt lgkmcnt(0)" ::: "memory"); // ds_writes visible
  __builtin_amdgcn_s_barrier();

  for (int t = 0; t < NT; ++t) {
    const int c = t & 1;
    const char* tb = lds + c * BUF;

    // ---- ph1: read af-lo, bf-lo; B pipeline ops; MFMA lo x lo ----
#pragma unroll
    for (int mi = 0; mi < MIL; ++mi) {
      int row = wm * (BM_ / 2) + mi * 16 + fr;
#pragma unroll
      for (int ks = 0; ks < 2; ++ks)
        af[mi][ks] = *(const short8*)(tb + row * 128 + ((ks * 64 + fq * 16) ^ ((row & 7) << 4)));
    }
#pragma unroll
    for (int ni = 0; ni < NFL; ++ni) {
      int row = wn * (BN_ / 4) + ni * 16 + fr;
#pragma unroll
      for (int ks = 0; ks < 2; ++ks)
        bf[ni][ks] = *(const short8*)(tb + ATILE + row * 128 + ((ks * 64 + fq * 16) ^ ((row & 7) << 4)));
    }
    asm volatile("s_waitcnt vmcnt(4)" ::: "memory"); // B-f32(t+1) regs ready (leaves A(t+1))
    if (t > 0 && t + 1 < NT) B_WRITE((t + 1) & 1);
    if (t + 2 < NT) B_ISSUE(t + 2);
    __builtin_amdgcn_s_barrier();
    __builtin_amdgcn_s_setprio(1);
#pragma unroll
    for (int mi = 0; mi < MIL; ++mi)
#pragma unroll
      for (int ni = 0; ni < NFL; ++ni)
#pragma unroll
        for (int ks = 0; ks < 2; ++ks)
          acc[mi][ni] = __builtin_amdgcn_mfma_f32_16x16x32_bf16(af[mi][ks], bf[ni][ks], acc[mi][ni], 0, 0, 0);
    __builtin_amdgcn_s_setprio(0);
    __builtin_amdgcn_s_barrier();

    // ---- ph2: read af-hi, bf-hi; MFMA lo x hi ----
#pragma unroll
    for (int mi = MIL; mi < MI; ++mi) {
      int row = wm * (BM_ / 2) + mi * 16 + fr;
#pragma unroll
      for (int ks = 0; ks < 2; ++ks)
        af[mi][ks] = *(const short8*)(tb + row * 128 + ((ks * 64 + fq * 16) ^ ((row & 7) << 4)));
    }
#pragma unroll
    for (int ni = NFL; ni < NF; ++ni) {
      int row = wn * (BN_ / 4) + ni * 16 + fr;
#pragma unroll
      for (int ks = 0; ks < 2; ++ks)
        bf[ni][ks] = *(const short8*)(tb + ATILE + row * 128 + ((ks * 64 + fq * 16) ^ ((row & 7) << 4)));
    }
    __builtin_amdgcn_s_barrier();
    __builtin_amdgcn_s_setprio(1);
#pragma unroll
    for (int mi = 0; mi < MIL; ++mi)
#pragma unroll
      for (int ni = NFL; ni < NF; ++ni)
#pragma unroll
        for (int ks = 0; ks < 2; ++ks)
          acc[mi][ni] = __builtin_amdgcn_mfma_f32_16x16x32_bf16(af[mi][ks], bf[ni][ks], acc[mi][ni], 0, 0, 0);
    __builtin_amdgcn_s_setprio(0);
    __builtin_amdgcn_s_barrier();

    // ---- ph3: stage A(t+2) into buf c (all buf-c reads done); MFMA hi x lo ----
    if (t + 2 < NT) STAGE_A(t + 2, c);
    __builtin_amdgcn_s_setprio(1);
#pragma unroll
    for (int mi = MIL; mi < MI; ++mi)
#pragma unroll
      for (int ni = 0; ni < NFL; ++ni)
#pragma unroll
        for (int ks = 0; ks < 2; ++ks)
          acc[mi][ni] = __builtin_amdgcn_mfma_f32_16x16x32_bf16(af[mi][ks], bf[ni][ks], acc[mi][ni], 0, 0, 0);
    __builtin_amdgcn_s_setprio(0);
    __builtin_amdgcn_s_barrier();

    // ---- ph4: MFMA hi x hi; counted vmcnt (drain A(t+1) only); barrier ----
    __builtin_amdgcn_s_setprio(1);
#pragma unroll
    for (int mi = MIL; mi < MI; ++mi)
#pragma unroll
      for (int ni = NFL; ni < NF; ++ni)
#pragma unroll
        for (int ks = 0; ks < 2; ++ks)
          acc[mi][ni] = __builtin_amdgcn_mfma_f32_16x16x32_bf16(af[mi][ks], bf[ni][ks], acc[mi][ni], 0, 0, 0);
    __builtin_amdgcn_s_setprio(0);
    if (t + 2 < NT) { asm volatile("s_waitcnt vmcnt(10)" ::: "memory"); }
    else if (t + 1 < NT) { asm volatile("s_waitcnt vmcnt(0)" ::: "memory"); }
    __builtin_amdgcn_s_barrier();
  }

#pragma unroll
  for (int mi = 0; mi < MI; ++mi)
#pragma unroll
    for (int ni = 0; ni < NF; ++ni)
#pragma unroll
      for (int j = 0; j < 4; ++j) {
        long r = m0 + wm * (BM_ / 2) + mi * 16 + fq * 4 + j;
        long cc = n0 + wn * (BN_ / 4) + ni * 16 + fr;
        Cv[r * N_ + cc] = f2bf(acc[mi][ni][j]);
      }
}

// ---------------- (BM x BN) 8-phase GEMM, 2-buffer (round-14 proven; out-proj) ----------------
template<int M_, int N_, int K_, int BM_, int BN_, int OUT_BF16, int CHN>
__global__ __launch_bounds__(512) void gemm8p(const unsigned short* __restrict__ A,
                                              const unsigned short* __restrict__ B,
                                              void* __restrict__ Cv) {
  constexpr int ATILE = BM_ * 128;
  constexpr int BTILE = BN_ * 128;
  constexpr int BUF = ATILE + BTILE;
  constexpr int LPA = BM_ / 64;
  constexpr int LPB = BN_ / 64;
  constexpr int VM  = LPA + LPB;
  constexpr int MI = BM_ / 32, NF = BN_ / 64;
  constexpr int MIL = MI / 2, NFL = NF / 2;
  constexpr int NT = K_ / 64;
  __shared__ char lds[2 * BUF];

  const int tid = threadIdx.x;
  const int lane = tid & 63, wave = tid >> 6;
  const int wm = wave >> 2, wn = wave & 3;
  const int fr = lane & 15, fq = lane >> 4;

  const int lin = blockIdx.x;
  const int xcd = lin & 7;
  const int slot = lin >> 3;
  const long n0 = (long)(xcd * CHN + slot % CHN) * BN_;
  const long m0 = (long)(slot / CHN) * BM_;

  auto STAGE_A = [&](int t, int c) {
#pragma unroll
    for (int u = 0; u < LPA; ++u) {
      int b = u * 8192 + tid * 16;
      int row = b >> 7;
      int off = (b & 127) ^ ((row & 7) << 4);
      __builtin_amdgcn_global_load_lds(
        (const __attribute__((address_space(1))) void*)((const char*)A + ((m0 + row) * (long)K_ + t * 64) * 2 + off),
        (__attribute__((address_space(3))) void*)(lds + c * BUF + b), 16, 0, 0);
    }
  };
  auto STAGE_B = [&](int t, int c) {
#pragma unroll
    for (int u = 0; u < LPB; ++u) {
      int b = u * 8192 + tid * 16;
      int row = b >> 7;
      int off = (b & 127) ^ ((row & 7) << 4);
      __builtin_amdgcn_global_load_lds(
        (const __attribute__((address_space(1))) void*)((const char*)B + ((n0 + row) * (long)K_ + t * 64) * 2 + off),
        (__attribute__((address_space(3))) void*)(lds + c * BUF + ATILE + b), 16, 0, 0);
    }
  };
#define VMCNT_STEADY() do { if constexpr (VM == 6) asm volatile("s_waitcnt vmcnt(6)" ::: "memory"); \
                            else if constexpr (VM == 7) asm volatile("s_waitcnt vmcnt(7)" ::: "memory"); \
                            else asm volatile("s_waitcnt vmcnt(8)" ::: "memory"); } while (0)

  f32x4 acc[MI][NF] = {};
  short8 af[MI][2];
  short8 bf[NF][2];

  STAGE_A(0, 0); STAGE_B(0, 0);
  STAGE_A(1, 1); STAGE_B(1, 1);
  VMCNT_STEADY();
  __builtin_amdgcn_s_barrier();

  for (int t = 0; t < NT; ++t) {
    const int c = t & 1;
    const char* tb = lds + c * BUF;

#pragma unroll
    for (int mi = 0; mi < MIL; ++mi) {
      int row = wm * (BM_ / 2) + mi * 16 + fr;
#pragma unroll
      for (int ks = 0; ks < 2; ++ks)
        af[mi][ks] = *(const short8*)(tb + row * 128 + ((ks * 64 + fq * 16) ^ ((row & 7) << 4)));
    }
#pragma unroll
    for (int ni = 0; ni < NFL; ++ni) {
      int row = wn * (BN_ / 4) + ni * 16 + fr;
#pragma unroll
      for (int ks = 0; ks < 2; ++ks)
        bf[ni][ks] = *(const short8*)(tb + ATILE + row * 128 + ((ks * 64 + fq * 16) ^ ((row & 7) << 4)));
    }
    __builtin_amdgcn_s_barrier();
    __builtin_amdgcn_s_setprio(1);
#pragma unroll
    for (int mi = 0; mi < MIL; ++mi)
#pragma unroll
      for (int ni = 0; ni < NFL; ++ni)
#pragma unroll
        for (int ks = 0; ks < 2; ++ks)
          acc[mi][ni] = __builtin_amdgcn_mfma_f32_16x16x32_bf16(af[mi][ks], bf[ni][ks], acc[mi][ni], 0, 0, 0);
    __builtin_amdgcn_s_setprio(0);
    __builtin_amdgcn_s_barrier();

#pragma unroll
    for (int mi = MIL; mi < MI; ++mi) {
      int row = wm * (BM_ / 2) + mi * 16 + fr;
#pragma unroll
      for (int ks = 0; ks < 2; ++ks)
        af[mi][ks] = *(const short8*)(tb + row * 128 + ((ks * 64 + fq * 16) ^ ((row & 7) << 4)));
    }
#pragma unroll
    for (int ni = NFL; ni < NF; ++ni) {
      int row = wn * (BN_ / 4) + ni * 16 + fr;
#pragma unroll
      for (int ks = 0; ks < 2; ++ks)
        bf[ni][ks] = *(const short8*)(tb + ATILE + row * 128 + ((ks * 64 + fq * 16) ^ ((row & 7) << 4)));
    }
    __builtin_amdgcn_s_barrier();
    __builtin_amdgcn_s_setprio(1);
#pragma unroll
    for (int mi = 0; mi < MIL; ++mi)
#pragma unroll
      for (int ni = NFL; ni < NF; ++ni)
#pragma unroll
        for (int ks = 0; ks < 2; ++ks)
          acc[mi][ni] = __builtin_amdgcn_mfma_f32_16x16x32_bf16(af[mi][ks], bf[ni][ks], acc[mi][ni], 0, 0, 0);
    __builtin_amdgcn_s_setprio(0);
    __builtin_amdgcn_s_barrier();

    if (t + 2 < NT) STAGE_A(t + 2, c);
    __builtin_amdgcn_s_setprio(1);
#pragma unroll
    for (int mi = MIL; mi < MI; ++mi)
#pragma unroll
      for (int ni = 0; ni < NFL; ++ni)
#pragma unroll
        for (int ks = 0; ks < 2; ++ks)
          acc[mi][ni] = __builtin_amdgcn_mfma_f32_16x16x32_bf16(af[mi][ks], bf[ni][ks], acc[mi][ni], 0, 0, 0);
    __builtin_amdgcn_s_setprio(0);
    __builtin_amdgcn_s_barrier();

    if (t + 2 < NT) STAGE_B(t + 2, c);
    __builtin_amdgcn_s_setprio(1);
#pragma unroll
    for (int mi = MIL; mi < MI; ++mi)
#pragma unroll
      for (int ni = NFL; ni < NF; ++ni)
#pragma unroll
        for (int ks = 0; ks < 2; ++ks)
          acc[mi][ni] = __builtin_amdgcn_mfma_f32_16x16x32_bf16(af[mi][ks], bf[ni][ks], acc[mi][ni], 0, 0, 0);
    __builtin_amdgcn_s_setprio(0);
    if (t + 2 < NT) { VMCNT_STEADY(); }
    else if (t + 1 < NT) { asm volatile("s_waitcnt vmcnt(0)" ::: "memory"); }
    __builtin_amdgcn_s_barrier();
  }
#undef VMCNT_STEADY

#pragma unroll
  for (int mi = 0; mi < MI; ++mi)
#pragma unroll
    for (int ni = 0; ni < NF; ++ni)
#pragma unroll
      for (int j = 0; j < 4; ++j) {
        long r = m0 + wm * (BM_ / 2) + mi * 16 + fq * 4 + j;
        long cc = n0 + wn * (BN_ / 4) + ni * 16 + fr;
        float v = acc[mi][ni][j];
        if (OUT_BF16) ((unsigned short*)Cv)[r * N_ + cc] = f2bf(v);
        else          ((float*)Cv)[r * N_ + cc] = v;
      }
}

// ---------------- merged: K-rope (blocks 0..4095) + V transpose (blocks 4096..4607) ----
__global__ __launch_bounds__(256) void ropek_tv(unsigned short* __restrict__ C,
                                                const float* __restrict__ cosb,
                                                const float* __restrict__ sinb,
                                                unsigned short* __restrict__ VT) {
  __shared__ unsigned short tbuf[64][72];
  const int blk = blockIdx.x;
  if (blk < 4096) {
    int idx = blk * 256 + threadIdx.x;   // 2048 s x 8 hh x 64 i
    int i = idx & 63;
    int t = idx >> 6;
    int hh = t & 7;
    int s = t >> 3;
    unsigned short* row = C + (size_t)s * NQKV + 4096 + hh * DH;
    float c  = cosb[s * DH + i];
    float sn = sinb[s * DH + i];
    float x1 = bf2f(row[i]);
    float x2 = bf2f(row[i + 64]);
    row[i]      = f2bf(x1 * c - x2 * sn);
    row[i + 64] = f2bf(x2 * c + x1 * sn);
    return;
  }
  const int b2 = blk - 4096;             // 512 blocks: 32 x 16
  const unsigned short* Vbuf = C + 5120;
  const int s0 = (b2 & 31) * 64, e0 = (b2 >> 5) * 64;
  const int r = threadIdx.x >> 3, c = (threadIdx.x & 7) * 8;
#pragma unroll
  for (int half = 0; half < 2; ++half) {
    int row = r + half * 32;
    *reinterpret_cast<short8*>(&tbuf[row][c]) =
        *reinterpret_cast<const short8*>(Vbuf + (size_t)(s0 + row) * NQKV + e0 + c);
  }
  __syncthreads();
  const int hh = e0 >> 7, dbase = e0 & 127;
#pragma unroll
  for (int half = 0; half < 2; ++half) {
    int row = r + half * 32;
    short8 o;
#pragma unroll
    for (int j = 0; j < 8; ++j) ((unsigned short*)&o)[j] = tbuf[c + j][row];
    *reinterpret_cast<short8*>(VT + (size_t)hh * (DH * (size_t)S_LEN)
                               + (size_t)(dbase + row) * S_LEN + s0 + c) = o;
  }
}

// ---------------- GQA causal flash attention + in-register Q-rope + Wo side-convert ----
__global__ __launch_bounds__(256) void attn_fwd(const unsigned short* __restrict__ C,
                                                const unsigned short* __restrict__ VT,
                                                unsigned short* __restrict__ Ob,
                                                const float* __restrict__ Wo,
                                                unsigned short* __restrict__ Wob,
                                                const float* __restrict__ cosb,
                                                const float* __restrict__ sinb) {
  __shared__ unsigned short KVs[2][8192];   // 16 KB/buf: K[32][128] swz @0, V^T[128][32] swz @8KB
  __shared__ unsigned short Pl[4][16 * 40];
  const int tid = threadIdx.x, lane = tid & 63, wave = tid >> 6;
  const int kvh = blockIdx.x & 7;
  const int p = blockIdx.x >> 3;
  const int h = kvh * 4 + wave;
  const int fr = lane & 15, fq = lane >> 4;
  const int q0s[2] = { p * 16, (127 - p) * 16 };
  const int tilesA = (p * 16 + 47) >> 5;
  const int tilesB = ((127 - p) * 16 + 47) >> 5;

  const unsigned short* Qbase = C + (size_t)h * DH;
  const unsigned short* Kbase = C + 4096 + (size_t)kvh * DH;
  const unsigned short* Vbase = VT + (size_t)kvh * (DH * (size_t)S_LEN);

  const int wq0 = blockIdx.x * 8192 + tid;
  float4 wreg;

  short8 qf[2][4];
#pragma unroll
  for (int s = 0; s < 2; ++s)
#pragma unroll
    for (int dc = 0; dc < 4; ++dc)
      qf[s][dc] = *reinterpret_cast<const short8*>(
          Qbase + (size_t)(q0s[s] + fr) * NQKV + dc * 32 + fq * 8);

  // in-register Q rope + SCALE: pair (d, d+64) = frags (dc, dc+2), same thread
#pragma unroll
  for (int s = 0; s < 2; ++s) {
    const int row = q0s[s] + fr;
#pragma unroll
    for (int dc = 0; dc < 2; ++dc)
#pragma unroll
      for (int e = 0; e < 8; ++e) {
        int d = dc * 32 + fq * 8 + e;
        float cs = cosb[row * DH + d];
        float sn = sinb[row * DH + d];
        float x1 = bf2f((unsigned short)qf[s][dc][e]);
        float x2 = bf2f((unsigned short)qf[s][dc + 2][e]);
        qf[s][dc][e]     = (short)f2bf((x1 * cs - x2 * sn) * SCALE);
        qf[s][dc + 2][e] = (short)f2bf((x2 * cs + x1 * sn) * SCALE);
      }
  }

  f32x4 o_acc[2][8] = {};
  float mrow[2][4] = {{-1e30f,-1e30f,-1e30f,-1e30f},{-1e30f,-1e30f,-1e30f,-1e30f}};
  float lpart[2][4] = {};

  auto STAGE = [&](int t, int buf) {
    const int kv0 = t * 32;
    char* dst = (char*)&KVs[buf][0];
#pragma unroll
    for (int sh = 0; sh < 2; ++sh) {
      int b = sh * 4096 + tid * 16;
      int krow = b >> 8;
      int kcol = (b & 255) ^ ((krow & 7) << 4);
      __builtin_amdgcn_global_load_lds(
          (const __attribute__((address_space(1))) void*)(Kbase + (size_t)(kv0 + krow) * NQKV + (kcol >> 1)),
          (__attribute__((address_space(3))) void*)(dst + b), 16, 0, 0);
      int vrow = b >> 6;
      int vcol = (b & 63) ^ ((((vrow ^ (vrow >> 2)) & 3)) << 4);
      __builtin_amdgcn_global_load_lds(
          (const __attribute__((address_space(1))) void*)(Vbase + (size_t)vrow * S_LEN + kv0 + (vcol >> 1)),
          (__attribute__((address_space(3))) void*)(dst + 8192 + b), 16, 0, 0);
    }
  };

  int cur = 0;
  STAGE(0, 0);
  asm volatile("s_waitcnt vmcnt(0)" ::: "memory");
  __syncthreads();

  for (int t = 0; t < tilesB; ++t) {
    const int kv0 = t * 32;

    // Wo side-convert: store chunk t-1 (completed by last tile's vmcnt(0)), load chunk t
    if (t > 0 && t <= 32) {
      us4 o;
      o.x = f2bf(wreg.x); o.y = f2bf(wreg.y); o.z = f2bf(wreg.z); o.w = f2bf(wreg.w);
      reinterpret_cast<us4*>(Wob)[wq0 + (t - 1) * 256] = o;
    }
    if (t < 32) wreg = reinterpret_cast<const float4*>(Wo)[wq0 + t * 256];

    if (t + 1 < tilesB) STAGE(t + 1, cur ^ 1);
    const char* kvb = (const char*)&KVs[cur][0];

#pragma unroll
    for (int s = 0; s < 2; ++s) {
      if (s == 0 && t >= tilesA) continue;
      const int q0 = q0s[s];

      f32x4 sacc[2] = {};
#pragma unroll
      for (int nt = 0; nt < 2; ++nt) {
        const int row = nt * 16 + fr;
#pragma unroll
        for (int dc = 0; dc < 4; ++dc) {
          short8 kf = *reinterpret_cast<const short8*>(
              kvb + row * 256 + ((dc * 64 + fq * 16) ^ ((row & 7) << 4)));
          sacc[nt] = __builtin_amdgcn_mfma_f32_16x16x32_bf16(qf[s][dc], kf, sacc[nt], 0, 0, 0);
        }
      }

      const bool needMask = (kv0 + 32 > q0);
      if (needMask) {
#pragma unroll
        for (int j = 0; j < 4; ++j) {
          int qrow = q0 + fq * 4 + j;
#pragma unroll
          for (int nt = 0; nt < 2; ++nt)
            sacc[nt][j] = ((kv0 + nt*16 + fr) <= qrow) ? sacc[nt][j] : -1e30f;
        }
      }
      bool ok = true;
      float lm[4];
#pragma unroll
      for (int j = 0; j < 4; ++j) {
        lm[j] = fmaxf(sacc[0][j], sacc[1][j]);
        ok = ok && (lm[j] <= mrow[s][j] + 8.f);
      }
      if (!__all(ok)) {
#pragma unroll
        for (int j = 0; j < 4; ++j) {
          float rm = lm[j];
          rm = fmaxf(rm, __shfl_xor(rm, 1));
          rm = fmaxf(rm, __shfl_xor(rm, 2));
          rm = fmaxf(rm, __shfl_xor(rm, 4));
          rm = fmaxf(rm, __shfl_xor(rm, 8));
          float mnew = fmaxf(mrow[s][j], rm);
          float corr = __expf(mrow[s][j] - mnew);
          mrow[s][j] = mnew;
          lpart[s][j] *= corr;
#pragma unroll
          for (int dt = 0; dt < 8; ++dt) o_acc[s][dt][j] *= corr;
        }
      }
#pragma unroll
      for (int j = 0; j < 4; ++j) {
        float p0 = __expf(sacc[0][j] - mrow[s][j]);
        float p1 = __expf(sacc[1][j] - mrow[s][j]);
        lpart[s][j] += p0 + p1;
        unsigned int u;
        asm("v_cvt_pk_bf16_f32 %0, %1, %2" : "=v"(u) : "v"(p0), "v"(p1));
        Pl[wave][(fq*4 + j)*40 + fr]      = (unsigned short)u;
        Pl[wave][(fq*4 + j)*40 + 16 + fr] = (unsigned short)(u >> 16);
      }
      asm volatile("s_waitcnt lgkmcnt(0)" ::: "memory");
      __builtin_amdgcn_sched_barrier(0);

      short8 pa = *reinterpret_cast<const short8*>(&Pl[wave][fr*40 + fq*8]);
#pragma unroll
      for (int dt = 0; dt < 8; ++dt) {
        const int row = dt * 16 + fr;
        short8 bv = *reinterpret_cast<const short8*>(
            kvb + 8192 + row * 64 + ((fq * 16) ^ ((((row ^ (row >> 2)) & 3)) << 4)));
        o_acc[s][dt] = __builtin_amdgcn_mfma_f32_16x16x32_bf16(pa, bv, o_acc[s][dt], 0, 0, 0);
      }
    }

    asm volatile("s_waitcnt vmcnt(0)" ::: "memory");
    __syncthreads();
    cur ^= 1;
  }

#pragma unroll
  for (int s = 0; s < 2; ++s)
#pragma unroll
    for (int j = 0; j < 4; ++j) {
      float l = lpart[s][j];
      l += __shfl_xor(l, 1);
      l += __shfl_xor(l, 2);
      l += __shfl_xor(l, 4);
      l += __shfl_xor(l, 8);
      float inv = 1.f / l;
      size_t r = (size_t)q0s[s] + fq*4 + j;
#pragma unroll
      for (int dt = 0; dt < 8; ++dt)
        Ob[r * QDIM + h * DH + dt*16 + fr] = f2bf(o_acc[s][dt][j] * inv);
    }
}

// ---------------- launch ----------------
extern "C" void kernel_launch(void* const* d_in, const int* in_sizes, int n_in,
                              void* d_out, int out_size, void* d_ws, size_t ws_size,
                              hipStream_t stream) {
  (void)in_sizes; (void)n_in; (void)out_size; (void)ws_size;
  const float* x    = (const float*)d_in[0];
  const float* Wq   = (const float*)d_in[1];
  const float* Wk   = (const float*)d_in[2];
  const float* Wv   = (const float*)d_in[3];
  const float* Wo   = (const float*)d_in[4];
  const float* cosb = (const float*)d_in[5];
  const float* sinb = (const float*)d_in[6];

  char* ws = (char*)d_ws;
  unsigned short* xb    = (unsigned short*)(ws);               // 16.8 MB (dead after QKV gemm)
  unsigned short* Wob   = (unsigned short*)(ws + 67108864);    // 33.6 MB (written by attn_fwd)
  unsigned short* Cqkv  = (unsigned short*)(ws + 100663296);   // 25.2 MB [Q|K|V] stride 6144
  unsigned short* VT    = (unsigned short*)(ws + 125829120);   // 4.2 MB
  unsigned short* Ab    = xb;                                  // reuse

  cvt_x<<<8192, 256, 0, stream>>>(x, xb);

  // QKV projection: B staged directly from f32 Wq/Wk/Wv (counted-vmcnt pipeline)
  gemm8pqkv<<<256, 512, 0, stream>>>(xb, Wq, Wk, Wv, Cqkv);

  // merged K-rope + V-transpose (Q rope happens in-register inside attn_fwd)
  ropek_tv<<<4608, 256, 0, stream>>>(Cqkv, cosb, sinb, VT);

  attn_fwd<<<512, 256, 0, stream>>>(Cqkv, VT, Ab, Wo, Wob, cosb, sinb);

  // Output projection: round-14 2-buffer schedule, 128x256 tiles -> 256 blocks (unchanged)
  gemm8p<2048, 4096, 4096, 128, 256, 0, 2><<<256, 512, 0, stream>>>(Ab, Wob, d_out);
}